// Round 1
// baseline (157.776 us; speedup 1.0000x reference)
//
#include <hip/hip_runtime.h>

// FFTPermuter: reference does y = x @ perm where perm is a one-hot
// permutation matrix (3-stage bit-reversal grouping), then splits y into
// 8 chunks along the last axis.
//
//   out_chunk[c][b,t,j] = x[b,t, j*8 + ms[c]],  ms = {0,4,2,6,1,5,3,7}
//
// Flat layout:
//   d_out[c*2^21 + t] = x[8*t + ms[c]],  t = row*512 + j  (row = b*512+tpos)
//
// Each thread owns 4 consecutive column indices t: reads 128 contiguous
// bytes (8x float4) and writes 8x float4, one per chunk, all streams fully
// coalesced. Pure HBM-bound permute: 64 MiB in + 64 MiB out.

#define NFFT        4096
#define BT          (8 * 512)               // 4096 rows
#define CHUNK_ELEMS (BT * 512)              // 2,097,152 elems per chunk
#define TOTAL_COLS  (BT * 512)              // 2^21 column slots
#define THREADS     (TOTAL_COLS / 4)        // each thread: 4 columns

__global__ __launch_bounds__(256) void
FFTPermuter_2748779070248_kernel(const float4* __restrict__ x4,
                                 float4* __restrict__ out4) {
    const int g = blockIdx.x * blockDim.x + threadIdx.x;   // 0 .. THREADS-1

    // Load 32 consecutive floats: columns 4g..4g+3, phases 0..7 each.
    // f[q*8 + p] = x[ (4g+q)*8 + p ]
    float f[32];
#pragma unroll
    for (int m = 0; m < 8; ++m) {
        float4 t = x4[(size_t)g * 8 + m];
        f[4 * m + 0] = t.x;
        f[4 * m + 1] = t.y;
        f[4 * m + 2] = t.z;
        f[4 * m + 3] = t.w;
    }

    const int ms[8] = {0, 4, 2, 6, 1, 5, 3, 7};   // 3-bit bit-reversal
#pragma unroll
    for (int c = 0; c < 8; ++c) {
        const int p = ms[c];
        float4 o;
        o.x = f[0 * 8 + p];
        o.y = f[1 * 8 + p];
        o.z = f[2 * 8 + p];
        o.w = f[3 * 8 + p];
        out4[(size_t)c * (CHUNK_ELEMS / 4) + g] = o;
    }
}

extern "C" void kernel_launch(void* const* d_in, const int* in_sizes, int n_in,
                              void* d_out, int out_size, void* d_ws, size_t ws_size,
                              hipStream_t stream) {
    const float4* x4   = (const float4*)d_in[0];   // x: [8,512,4096] fp32
    float4*       out4 = (float4*)d_out;           // 8 chunks of [8,512,512] fp32
    // d_in[1] (perm) is a compile-time-known one-hot matrix; never read.

    const int threads = THREADS;                   // 524,288
    const int block   = 256;
    const int grid    = threads / block;           // 2048 blocks
    FFTPermuter_2748779070248_kernel<<<grid, block, 0, stream>>>(x4, out4);
}

// Round 2
// 155.086 us; speedup vs baseline: 1.0173x; 1.0173x over previous
//
#include <hip/hip_runtime.h>

// FFTPermuter: out_chunk[c][col] = x[8*col + ms[c]], ms = {0,4,2,6,1,5,3,7}
// (perm is a compile-time one-hot matrix; never read).
//
// R1 analysis: R0's loads had 128B lane-stride (8x request inflation per
// global_load_dwordx4) -> 2.4 TB/s. This version stages through LDS so both
// global loads and stores are lane-consecutive float4 (16B/lane dense):
//
//   phase 1: block loads 1024 columns (32 KiB) coalesced, scatters into
//            LDS column-major lds[phase*1024 + col] (2-way bank = free)
//   phase 2: ds_read_b128 (4 cols x 1 phase), coalesced float4 store per chunk

#define COLS_TOTAL  (8u * 512u * 512u)     // 2^21 column slots
#define TILE_COLS   1024
#define BLOCK       256

__global__ __launch_bounds__(BLOCK) void
FFTPermuter_2748779070248_kernel(const float4* __restrict__ x4,
                                 float4* __restrict__ out4) {
    __shared__ __align__(16) float lds[8 * TILE_COLS];   // [phase][col], 32 KiB

    const int    tid   = threadIdx.x;
    const size_t tile  = blockIdx.x;          // 2048 tiles
    const size_t base4 = tile * 2048;         // 2048 float4 of input per tile

    // ---- phase 1: coalesced global load -> LDS transpose-scatter ----
#pragma unroll
    for (int k = 0; k < 8; ++k) {
        const int e4 = k * BLOCK + tid;       // float4 index within tile, 0..2047
        float4 v = x4[base4 + e4];
        const int col = e4 >> 1;              // 0..1023
        const int ph0 = (e4 & 1) * 4;         // phases 0-3 or 4-7
        lds[(ph0 + 0) * TILE_COLS + col] = v.x;
        lds[(ph0 + 1) * TILE_COLS + col] = v.y;
        lds[(ph0 + 2) * TILE_COLS + col] = v.z;
        lds[(ph0 + 3) * TILE_COLS + col] = v.w;
    }
    __syncthreads();

    // ---- phase 2: ds_read_b128 per phase, coalesced float4 store per chunk ----
    const int ms[8] = {0, 4, 2, 6, 1, 5, 3, 7};   // 3-bit bit-reversal
    const size_t colbase4 = tile * (TILE_COLS / 4);
#pragma unroll
    for (int c = 0; c < 8; ++c) {
        const int p = ms[c];
        const float4 o = *(const float4*)&lds[p * TILE_COLS + 4 * tid];
        out4[(size_t)c * (COLS_TOTAL / 4) + colbase4 + tid] = o;
    }
}

extern "C" void kernel_launch(void* const* d_in, const int* in_sizes, int n_in,
                              void* d_out, int out_size, void* d_ws, size_t ws_size,
                              hipStream_t stream) {
    const float4* x4   = (const float4*)d_in[0];   // x: [8,512,4096] fp32
    float4*       out4 = (float4*)d_out;           // 8 chunks of [8,512,512] fp32

    const int grid = COLS_TOTAL / TILE_COLS;       // 2048 blocks
    FFTPermuter_2748779070248_kernel<<<grid, BLOCK, 0, stream>>>(x4, out4);
}